// Round 2
// baseline (800.670 us; speedup 1.0000x reference)
//
#include <hip/hip_runtime.h>

#define NN 100000
#define NE 1600000
#define FIN 256
#define FHID 128
#define FCLS 64

// bucket sort params: 128 nodes per bucket
#define BSH 7
#define NB ((NN + 127) / 128)   // 782
#define BCAP 2560               // mean 2048, +11 sigma

typedef _Float16 f16;
typedef __attribute__((ext_vector_type(8))) _Float16 f16x8;
typedef __attribute__((ext_vector_type(2))) _Float16 f16x2;
typedef __attribute__((ext_vector_type(4))) float f32x4;

// ---------------- pass 1: bin edges by dst bucket, count outdeg ----------------
__global__ __launch_bounds__(256) void k_bin(const int* __restrict__ src, const int* __restrict__ dst,
                                             int* __restrict__ outdeg, int* __restrict__ bcnt,
                                             unsigned* __restrict__ pairs) {
  int e = blockIdx.x * 256 + threadIdx.x;
  if (e < NE) {
    int s = src[e], d = dst[e];
    atomicAdd(&outdeg[s], 1);
    int b = d >> BSH;
    int p = atomicAdd(&bcnt[b], 1);
    if (p < BCAP) pairs[(size_t)b * BCAP + p] = ((unsigned)s << BSH) | (unsigned)(d & 127);
  }
}

// ---------------- pass 2: exclusive scan of bucket counts (NB=782 <= 1024) ----------------
__global__ __launch_bounds__(1024) void k_bscan(const int* __restrict__ bcnt, int* __restrict__ ebase,
                                                int* __restrict__ rp) {
  __shared__ int sm[1024];
  int t = threadIdx.x;
  int v = (t < NB) ? bcnt[t] : 0;
  int x = v;
  sm[t] = x;
  __syncthreads();
  for (int off = 1; off < 1024; off <<= 1) {
    int y = (t >= off) ? sm[t - off] : 0;
    __syncthreads();
    x += y;
    sm[t] = x;
    __syncthreads();
  }
  if (t < NB) ebase[t] = x - v;
  if (t == 0) rp[NN] = NE;
}

// ---------------- pass 3: per-bucket CSR build (LDS hist + prefix + fill) ----------------
__global__ __launch_bounds__(256) void k_build(const unsigned* __restrict__ pairs, const int* __restrict__ bcnt,
                                               const int* __restrict__ ebase, int* __restrict__ rp,
                                               float* __restrict__ inorm, int* __restrict__ csr) {
  __shared__ int lcnt[128], lofs[128], lcur[128];
  int b = blockIdx.x;
  int t = threadIdx.x;
  int cnt = bcnt[b];
  if (cnt > BCAP) cnt = BCAP;
  int eb = ebase[b];
  if (t < 128) lcnt[t] = 0;
  __syncthreads();
  const unsigned* pp = pairs + (size_t)b * BCAP;
  for (int i = t; i < cnt; i += 256) atomicAdd(&lcnt[pp[i] & 127], 1);
  __syncthreads();
  if (t < 128) lofs[t] = lcnt[t];
  __syncthreads();
  for (int off = 1; off < 128; off <<= 1) {  // Hillis-Steele inclusive scan
    int y = 0;
    if (t < 128 && t >= off) y = lofs[t - off];
    __syncthreads();
    if (t < 128) lofs[t] += y;
    __syncthreads();
  }
  if (t < 128) {
    int excl = lofs[t] - lcnt[t];
    lofs[t] = excl;
    lcur[t] = 0;
    int node = (b << BSH) + t;
    if (node < NN) {
      rp[node] = eb + excl;
      int deg = lcnt[t];
      if (deg < 1) deg = 1;
      inorm[node] = rsqrtf((float)deg);
    }
  }
  __syncthreads();
  for (int i = t; i < cnt; i += 256) {
    unsigned pr = pp[i];
    int d7 = pr & 127;
    int pos = eb + lofs[d7] + atomicAdd(&lcur[d7], 1);
    csr[pos] = (int)(pr >> BSH);
  }
}

__global__ __launch_bounds__(256) void k_onorm(const int* __restrict__ outdeg, float* __restrict__ onorm) {
  int i = blockIdx.x * 256 + threadIdx.x;
  if (i < NN) {
    int od = outdeg[i];
    if (od < 1) od = 1;
    onorm[i] = rsqrtf((float)od);
  }
}

// ---------------- weight pack: fragment-major f16 for mfma 16x16x32 ----------------
template <int K, int NW>
__global__ __launch_bounds__(256) void k_packw(const float* __restrict__ W, f16* __restrict__ Wp) {
  int idx = blockIdx.x * 256 + threadIdx.x;
  if (idx >= K * NW) return;
  constexpr int nT = NW / 16;
  int i = idx & 7;
  int l = (idx >> 3) & 63;
  int rest = idx >> 9;
  int t = rest % nT;
  int s = rest / nT;
  int k = s * 32 + (l >> 4) * 8 + i;
  int n = t * 16 + (l & 15);
  Wp[idx] = (f16)W[k * NW + n];
}

// ---------------- GEMM: [M=NN x K] @ [K x NW] via mfma_f32_16x16x32_f16 ----------------
// MODE 0: A = f32 x, rows scaled by onorm[row]; store f16 plain.
// MODE 1: A = f16; store f16 plain.
// MODE 2: A = f16; store f16 relu(acc + bias[col]) * onorm[row].
template <int K, int NW, int MODE>
__global__ __launch_bounds__(256) void k_gemm(const void* __restrict__ Asrc, const f16* __restrict__ Wp,
                                              const float* __restrict__ onorm, const float* __restrict__ bias,
                                              f16* __restrict__ Out) {
  constexpr int nS = K / 32, nT = NW / 16;
  int lane = threadIdx.x & 63;
  int w = threadIdx.x >> 6;
  int bm = blockIdx.x * 64 + w * 16;
  int arow = bm + (lane & 15);
  int koff = (lane >> 4) * 8;
  bool rowok = arow < NN;

  f32x4 acc[nT];
#pragma unroll
  for (int t = 0; t < nT; ++t) acc[t] = (f32x4){0.f, 0.f, 0.f, 0.f};

  float ascale = 0.0f;
  if (MODE == 0) ascale = rowok ? onorm[arow] : 0.0f;

  for (int s = 0; s < nS; ++s) {
    f16x8 a = {};
    if (rowok) {
      if (MODE == 0) {
        const float* ap = (const float*)Asrc + (size_t)arow * K + s * 32 + koff;
        f32x4 v0 = *(const f32x4*)ap;
        f32x4 v1 = *(const f32x4*)(ap + 4);
#pragma unroll
        for (int j = 0; j < 4; ++j) {
          a[j] = (f16)(v0[j] * ascale);
          a[4 + j] = (f16)(v1[j] * ascale);
        }
      } else {
        a = *(const f16x8*)((const f16*)Asrc + (size_t)arow * K + s * 32 + koff);
      }
    }
    const f16* bp = Wp + ((size_t)(s * nT) * 64 + lane) * 8;
#pragma unroll
    for (int t = 0; t < nT; ++t) {
      f16x8 bfr = *(const f16x8*)(bp + t * 512);
      acc[t] = __builtin_amdgcn_mfma_f32_16x16x32_f16(a, bfr, acc[t], 0, 0, 0);
    }
  }

  int crow0 = bm + (lane >> 4) * 4;
  int ccol = lane & 15;
#pragma unroll
  for (int t = 0; t < nT; ++t) {
#pragma unroll
    for (int r = 0; r < 4; ++r) {
      int row = crow0 + r;
      if (row >= NN) continue;
      int col = t * 16 + ccol;
      float v = acc[t][r];
      if (MODE == 2) v = fmaxf(v + bias[col], 0.f) * onorm[row];
      Out[(size_t)row * NW + col] = (f16)v;
    }
  }
}

// ---------------- aggregation: per-node gather-sum over CSR in-edges ----------------
// MODE 0: out f16 = relu(acc*inorm + bias[f]) * onorm[node]
// MODE 1: out f16 = acc*inorm
// MODE 2: out f32 = acc*inorm + bias[f]
template <int W, int MODE>
__global__ __launch_bounds__(256) void k_agg(const f16* __restrict__ src_arr, const int* __restrict__ rp,
                                             const int* __restrict__ csr, const float* __restrict__ inorm,
                                             const float* __restrict__ onorm, const float* __restrict__ bias,
                                             void* __restrict__ outp) {
  constexpr int LPN = W / 2;
  int tid = blockIdx.x * 256 + threadIdx.x;
  int node = tid / LPN;
  int fo = (tid % LPN) * 2;
  if (node >= NN) return;
  int beg = rp[node], end = rp[node + 1];
  float a0 = 0.f, a1 = 0.f;
  int e = beg;
  for (; e + 1 < end; e += 2) {
    int s0 = csr[e], s1 = csr[e + 1];
    f16x2 v0 = *(const f16x2*)(src_arr + (size_t)s0 * W + fo);
    f16x2 v1 = *(const f16x2*)(src_arr + (size_t)s1 * W + fo);
    a0 += (float)v0[0] + (float)v1[0];
    a1 += (float)v0[1] + (float)v1[1];
  }
  if (e < end) {
    int s0 = csr[e];
    f16x2 v0 = *(const f16x2*)(src_arr + (size_t)s0 * W + fo);
    a0 += (float)v0[0];
    a1 += (float)v0[1];
  }
  float inn = inorm[node];
  if (MODE == 0) {
    float on = onorm[node];
    f16x2 o;
    o[0] = (f16)(fmaxf(a0 * inn + bias[fo], 0.f) * on);
    o[1] = (f16)(fmaxf(a1 * inn + bias[fo + 1], 0.f) * on);
    *(f16x2*)((f16*)outp + (size_t)node * W + fo) = o;
  } else if (MODE == 1) {
    f16x2 o;
    o[0] = (f16)(a0 * inn);
    o[1] = (f16)(a1 * inn);
    *(f16x2*)((f16*)outp + (size_t)node * W + fo) = o;
  } else {
    float* op = (float*)outp + (size_t)node * W + fo;
    op[0] = a0 * inn + bias[fo];
    op[1] = a1 * inn + bias[fo + 1];
  }
}

extern "C" void kernel_launch(void* const* d_in, const int* in_sizes, int n_in,
                              void* d_out, int out_size, void* d_ws, size_t ws_size,
                              hipStream_t stream) {
  const float* x = (const float*)d_in[0];
  const int* src = (const int*)d_in[1];
  const int* dst = (const int*)d_in[2];
  const float* W1 = (const float*)d_in[3];
  const float* b1 = (const float*)d_in[4];
  const float* W2 = (const float*)d_in[5];
  const float* b2 = (const float*)d_in[6];
  const float* W3 = (const float*)d_in[7];
  const float* b3 = (const float*)d_in[8];

  char* base = (char*)d_ws;
  size_t off = 0;
  auto take = [&](size_t bytes) -> void* {
    void* r = base + off;
    off += (bytes + 255) & ~(size_t)255;
    return r;
  };
  int* outdeg = (int*)take((size_t)NN * 4);
  float* onorm = (float*)take((size_t)NN * 4);
  float* inorm = (float*)take((size_t)NN * 4);
  int* rp = (int*)take((size_t)(NN + 1) * 4);
  int* bcnt = (int*)take((size_t)NB * 4);
  int* ebase = (int*)take((size_t)NB * 4);
  unsigned* pairs = (unsigned*)take((size_t)NB * BCAP * 4);  // 8.0 MB
  int* csr = (int*)take((size_t)NE * 4);
  f16* W1p = (f16*)take((size_t)FIN * FHID * 2);
  f16* W2p = (f16*)take((size_t)FHID * FHID * 2);
  f16* W3p = (f16*)take((size_t)FHID * FCLS * 2);
  f16* B1 = (f16*)take((size_t)NN * FHID * 2);
  f16* B2 = (f16*)take((size_t)NN * FHID * 2);

  hipMemsetAsync(outdeg, 0, (size_t)NN * 4, stream);
  hipMemsetAsync(bcnt, 0, (size_t)NB * 4, stream);

  int nb = (NN + 255) / 256;
  k_bin<<<(NE + 255) / 256, 256, 0, stream>>>(src, dst, outdeg, bcnt, pairs);
  k_bscan<<<1, 1024, 0, stream>>>(bcnt, ebase, rp);
  k_build<<<NB, 256, 0, stream>>>(pairs, bcnt, ebase, rp, inorm, csr);
  k_onorm<<<nb, 256, 0, stream>>>(outdeg, onorm);

  k_packw<FIN, FHID><<<(FIN * FHID + 255) / 256, 256, 0, stream>>>(W1, W1p);
  k_packw<FHID, FHID><<<(FHID * FHID + 255) / 256, 256, 0, stream>>>(W2, W2p);
  k_packw<FHID, FCLS><<<(FHID * FCLS + 255) / 256, 256, 0, stream>>>(W3, W3p);

  const int gemm_grid = (NN + 63) / 64;
  // layer 1: t1 = (x*onorm) @ W1
  k_gemm<FIN, FHID, 0><<<gemm_grid, 256, 0, stream>>>(x, W1p, onorm, nullptr, B1);
  // g1 = relu(agg(t1)*inorm + b1) * onorm
  k_agg<FHID, 0><<<(NN * (FHID / 2) + 255) / 256, 256, 0, stream>>>(B1, rp, csr, inorm, onorm, b1, B2);
  // agg2 = agg(g1)*inorm
  k_agg<FHID, 1><<<(NN * (FHID / 2) + 255) / 256, 256, 0, stream>>>(B2, rp, csr, inorm, nullptr, nullptr, B1);
  // g2 = relu(agg2 @ W2 + b2) * onorm
  k_gemm<FHID, FHID, 2><<<gemm_grid, 256, 0, stream>>>(B1, W2p, onorm, b2, B2);
  // t3 = g2 @ W3
  k_gemm<FHID, FCLS, 1><<<gemm_grid, 256, 0, stream>>>(B2, W3p, nullptr, nullptr, B1);
  // out = agg(t3)*inorm + b3
  k_agg<FCLS, 2><<<(NN * (FCLS / 2) + 255) / 256, 256, 0, stream>>>(B1, rp, csr, inorm, nullptr, b3, d_out);
}

// Round 3
// 451.041 us; speedup vs baseline: 1.7752x; 1.7752x over previous
//
#include <hip/hip_runtime.h>

#define NN 100000
#define NE 1600000
#define FIN 256
#define FHID 128
#define FCLS 64

// multisplit params: 512 dst-nodes per partition
#define SH1 9
#define P1 196                       // ceil(100000/512)
#define EPB 8192                     // edges per block in hist/place
#define NBLK_E ((NE + EPB - 1) / EPB)  // 196

typedef _Float16 f16;
typedef __attribute__((ext_vector_type(8))) _Float16 f16x8;
typedef __attribute__((ext_vector_type(2))) _Float16 f16x2;
typedef __attribute__((ext_vector_type(4))) float f32x4;

// ---------------- pass A: per-block dst-partition histogram + outdeg ----------------
__global__ __launch_bounds__(256) void k_histA(const int* __restrict__ src, const int* __restrict__ dst,
                                               int* __restrict__ outdeg, int* __restrict__ hist2d) {
  __shared__ int lh[P1];
  int t = threadIdx.x;
  for (int i = t; i < P1; i += 256) lh[i] = 0;
  __syncthreads();
  int base = blockIdx.x * EPB;
  int cnt = NE - base; if (cnt > EPB) cnt = EPB;
  for (int i = t; i < cnt; i += 256) {
    atomicAdd(&outdeg[src[base + i]], 1);
    atomicAdd(&lh[dst[base + i] >> SH1], 1);
  }
  __syncthreads();
  for (int i = t; i < P1; i += 256) hist2d[blockIdx.x * P1 + i] = lh[i];
}

// ---------------- pass B: totals, partition bases, per-(block,partition) bases ----------------
__global__ __launch_bounds__(256) void k_pscan(const int* __restrict__ hist2d, int* __restrict__ totals,
                                               int* __restrict__ pbase, int* __restrict__ base2d,
                                               int* __restrict__ rp) {
  __shared__ int sm[256];
  int t = threadIdx.x;
  int tot = 0;
  if (t < P1) {
    for (int b = 0; b < NBLK_E; ++b) tot += hist2d[b * P1 + t];
    totals[t] = tot;
  }
  int v = (t < P1) ? tot : 0;
  int x = v;
  sm[t] = x;
  __syncthreads();
  for (int off = 1; off < 256; off <<= 1) {
    int y = (t >= off) ? sm[t - off] : 0;
    __syncthreads();
    x += y;
    sm[t] = x;
    __syncthreads();
  }
  if (t < P1) {
    int run = x - v;
    pbase[t] = run;
    for (int b = 0; b < NBLK_E; ++b) {
      base2d[b * P1 + t] = run;
      run += hist2d[b * P1 + t];
    }
  }
  if (t == 0) rp[NN] = NE;
}

// ---------------- pass C: per-block LDS counting sort -> contiguous partition runs ----------------
__global__ __launch_bounds__(256) void k_place(const int* __restrict__ src, const int* __restrict__ dst,
                                               const int* __restrict__ hist2d, const int* __restrict__ base2d,
                                               unsigned* __restrict__ staged) {
  __shared__ unsigned buf[EPB];
  __shared__ unsigned char prt[EPB];
  __shared__ int lofs[P1], lcur[P1], lbase[P1];
  __shared__ int sm[256];
  int t = threadIdx.x;
  int b = blockIdx.x;
  int v = 0;
  if (t < P1) {
    v = hist2d[b * P1 + t];
    lbase[t] = base2d[b * P1 + t];
    lcur[t] = 0;
  }
  int x = v;
  sm[t] = x;
  __syncthreads();
  for (int off = 1; off < 256; off <<= 1) {
    int y = (t >= off) ? sm[t - off] : 0;
    __syncthreads();
    x += y;
    sm[t] = x;
    __syncthreads();
  }
  if (t < P1) lofs[t] = x - v;
  __syncthreads();
  int base = b * EPB;
  int cnt = NE - base; if (cnt > EPB) cnt = EPB;
  for (int i = t; i < cnt; i += 256) {
    int s = src[base + i], d = dst[base + i];
    int p = d >> SH1;
    int pos = lofs[p] + atomicAdd(&lcur[p], 1);
    buf[pos] = ((unsigned)s << SH1) | (unsigned)(d & 511);
    prt[pos] = (unsigned char)p;
  }
  __syncthreads();
  for (int i = t; i < cnt; i += 256) {
    int p = prt[i];
    staged[lbase[p] + (i - lofs[p])] = buf[i];
  }
}

// ---------------- pass D: per-partition CSR build (512 nodes, dense I/O) ----------------
__global__ __launch_bounds__(512) void k_buildp(const unsigned* __restrict__ staged, const int* __restrict__ totals,
                                                const int* __restrict__ pbase, int* __restrict__ rp,
                                                float* __restrict__ inorm, int* __restrict__ csr) {
  __shared__ int lcnt[512], lofs[512], lcur[512];
  int p = blockIdx.x, t = threadIdx.x;
  int pb = pbase[p], cnt = totals[p];
  lcnt[t] = 0;
  __syncthreads();
  const unsigned* sp = staged + pb;
  for (int i = t; i < cnt; i += 512) atomicAdd(&lcnt[sp[i] & 511], 1);
  __syncthreads();
  int v = lcnt[t];
  int x = v;
  lofs[t] = x;
  __syncthreads();
  for (int off = 1; off < 512; off <<= 1) {
    int y = (t >= off) ? lofs[t - off] : 0;
    __syncthreads();
    x += y;
    lofs[t] = x;
    __syncthreads();
  }
  int excl = x - v;
  lofs[t] = excl;
  lcur[t] = 0;
  int node = (p << SH1) + t;
  if (node < NN) {
    rp[node] = pb + excl;
    int dg = v < 1 ? 1 : v;
    inorm[node] = rsqrtf((float)dg);
  }
  __syncthreads();
  for (int i = t; i < cnt; i += 512) {
    unsigned e = sp[i];
    int d = e & 511;
    int pos = pb + lofs[d] + atomicAdd(&lcur[d], 1);
    csr[pos] = (int)(e >> SH1);
  }
}

__global__ __launch_bounds__(256) void k_onorm(const int* __restrict__ outdeg, float* __restrict__ onorm) {
  int i = blockIdx.x * 256 + threadIdx.x;
  if (i < NN) {
    int od = outdeg[i];
    if (od < 1) od = 1;
    onorm[i] = rsqrtf((float)od);
  }
}

// ---------------- weight pack: fragment-major f16 for mfma 16x16x32 ----------------
template <int K, int NW>
__global__ __launch_bounds__(256) void k_packw(const float* __restrict__ W, f16* __restrict__ Wp) {
  int idx = blockIdx.x * 256 + threadIdx.x;
  if (idx >= K * NW) return;
  constexpr int nT = NW / 16;
  int i = idx & 7;
  int l = (idx >> 3) & 63;
  int rest = idx >> 9;
  int t = rest % nT;
  int s = rest / nT;
  int k = s * 32 + (l >> 4) * 8 + i;
  int n = t * 16 + (l & 15);
  Wp[idx] = (f16)W[k * NW + n];
}

// ---------------- GEMM: [M=NN x K] @ [K x NW] via mfma_f32_16x16x32_f16 ----------------
template <int K, int NW, int MODE>
__global__ __launch_bounds__(256) void k_gemm(const void* __restrict__ Asrc, const f16* __restrict__ Wp,
                                              const float* __restrict__ onorm, const float* __restrict__ bias,
                                              f16* __restrict__ Out) {
  constexpr int nS = K / 32, nT = NW / 16;
  int lane = threadIdx.x & 63;
  int w = threadIdx.x >> 6;
  int bm = blockIdx.x * 64 + w * 16;
  int arow = bm + (lane & 15);
  int koff = (lane >> 4) * 8;
  bool rowok = arow < NN;

  f32x4 acc[nT];
#pragma unroll
  for (int t = 0; t < nT; ++t) acc[t] = (f32x4){0.f, 0.f, 0.f, 0.f};

  float ascale = 0.0f;
  if (MODE == 0) ascale = rowok ? onorm[arow] : 0.0f;

  for (int s = 0; s < nS; ++s) {
    f16x8 a = {};
    if (rowok) {
      if (MODE == 0) {
        const float* ap = (const float*)Asrc + (size_t)arow * K + s * 32 + koff;
        f32x4 v0 = *(const f32x4*)ap;
        f32x4 v1 = *(const f32x4*)(ap + 4);
#pragma unroll
        for (int j = 0; j < 4; ++j) {
          a[j] = (f16)(v0[j] * ascale);
          a[4 + j] = (f16)(v1[j] * ascale);
        }
      } else {
        a = *(const f16x8*)((const f16*)Asrc + (size_t)arow * K + s * 32 + koff);
      }
    }
    const f16* bp = Wp + ((size_t)(s * nT) * 64 + lane) * 8;
#pragma unroll
    for (int t = 0; t < nT; ++t) {
      f16x8 bfr = *(const f16x8*)(bp + t * 512);
      acc[t] = __builtin_amdgcn_mfma_f32_16x16x32_f16(a, bfr, acc[t], 0, 0, 0);
    }
  }

  int crow0 = bm + (lane >> 4) * 4;
  int ccol = lane & 15;
#pragma unroll
  for (int t = 0; t < nT; ++t) {
#pragma unroll
    for (int r = 0; r < 4; ++r) {
      int row = crow0 + r;
      if (row >= NN) continue;
      int col = t * 16 + ccol;
      float v = acc[t][r];
      if (MODE == 2) v = fmaxf(v + bias[col], 0.f) * onorm[row];
      Out[(size_t)row * NW + col] = (f16)v;
    }
  }
}

// ---------------- aggregation: per-node gather-sum over CSR in-edges ----------------
template <int W, int MODE>
__global__ __launch_bounds__(256) void k_agg(const f16* __restrict__ src_arr, const int* __restrict__ rp,
                                             const int* __restrict__ csr, const float* __restrict__ inorm,
                                             const float* __restrict__ onorm, const float* __restrict__ bias,
                                             void* __restrict__ outp) {
  constexpr int LPN = W / 2;
  int tid = blockIdx.x * 256 + threadIdx.x;
  int node = tid / LPN;
  int fo = (tid % LPN) * 2;
  if (node >= NN) return;
  int beg = rp[node], end = rp[node + 1];
  float a0 = 0.f, a1 = 0.f;
  int e = beg;
  for (; e + 1 < end; e += 2) {
    int s0 = csr[e], s1 = csr[e + 1];
    f16x2 v0 = *(const f16x2*)(src_arr + (size_t)s0 * W + fo);
    f16x2 v1 = *(const f16x2*)(src_arr + (size_t)s1 * W + fo);
    a0 += (float)v0[0] + (float)v1[0];
    a1 += (float)v0[1] + (float)v1[1];
  }
  if (e < end) {
    int s0 = csr[e];
    f16x2 v0 = *(const f16x2*)(src_arr + (size_t)s0 * W + fo);
    a0 += (float)v0[0];
    a1 += (float)v0[1];
  }
  float inn = inorm[node];
  if (MODE == 0) {
    float on = onorm[node];
    f16x2 o;
    o[0] = (f16)(fmaxf(a0 * inn + bias[fo], 0.f) * on);
    o[1] = (f16)(fmaxf(a1 * inn + bias[fo + 1], 0.f) * on);
    *(f16x2*)((f16*)outp + (size_t)node * W + fo) = o;
  } else if (MODE == 1) {
    f16x2 o;
    o[0] = (f16)(a0 * inn);
    o[1] = (f16)(a1 * inn);
    *(f16x2*)((f16*)outp + (size_t)node * W + fo) = o;
  } else {
    float* op = (float*)outp + (size_t)node * W + fo;
    op[0] = a0 * inn + bias[fo];
    op[1] = a1 * inn + bias[fo + 1];
  }
}

extern "C" void kernel_launch(void* const* d_in, const int* in_sizes, int n_in,
                              void* d_out, int out_size, void* d_ws, size_t ws_size,
                              hipStream_t stream) {
  const float* x = (const float*)d_in[0];
  const int* src = (const int*)d_in[1];
  const int* dst = (const int*)d_in[2];
  const float* W1 = (const float*)d_in[3];
  const float* b1 = (const float*)d_in[4];
  const float* W2 = (const float*)d_in[5];
  const float* b2 = (const float*)d_in[6];
  const float* W3 = (const float*)d_in[7];
  const float* b3 = (const float*)d_in[8];

  char* base = (char*)d_ws;
  size_t off = 0;
  auto take = [&](size_t bytes) -> void* {
    void* r = base + off;
    off += (bytes + 255) & ~(size_t)255;
    return r;
  };
  int* outdeg = (int*)take((size_t)NN * 4);
  float* onorm = (float*)take((size_t)NN * 4);
  float* inorm = (float*)take((size_t)NN * 4);
  int* rp = (int*)take((size_t)(NN + 1) * 4);
  int* totals = (int*)take((size_t)P1 * 4);
  int* pbase = (int*)take((size_t)P1 * 4);
  int* hist2d = (int*)take((size_t)NBLK_E * P1 * 4);
  int* base2d = (int*)take((size_t)NBLK_E * P1 * 4);
  unsigned* staged = (unsigned*)take((size_t)NE * 4);
  int* csr = (int*)take((size_t)NE * 4);
  f16* W1p = (f16*)take((size_t)FIN * FHID * 2);
  f16* W2p = (f16*)take((size_t)FHID * FHID * 2);
  f16* W3p = (f16*)take((size_t)FHID * FCLS * 2);
  f16* B1 = (f16*)take((size_t)NN * FHID * 2);
  f16* B2 = (f16*)take((size_t)NN * FHID * 2);

  hipMemsetAsync(outdeg, 0, (size_t)NN * 4, stream);

  k_histA<<<NBLK_E, 256, 0, stream>>>(src, dst, outdeg, hist2d);
  k_pscan<<<1, 256, 0, stream>>>(hist2d, totals, pbase, base2d, rp);
  k_place<<<NBLK_E, 256, 0, stream>>>(src, dst, hist2d, base2d, staged);
  k_buildp<<<P1, 512, 0, stream>>>(staged, totals, pbase, rp, inorm, csr);
  k_onorm<<<(NN + 255) / 256, 256, 0, stream>>>(outdeg, onorm);

  k_packw<FIN, FHID><<<(FIN * FHID + 255) / 256, 256, 0, stream>>>(W1, W1p);
  k_packw<FHID, FHID><<<(FHID * FHID + 255) / 256, 256, 0, stream>>>(W2, W2p);
  k_packw<FHID, FCLS><<<(FHID * FCLS + 255) / 256, 256, 0, stream>>>(W3, W3p);

  const int gemm_grid = (NN + 63) / 64;
  // layer 1: t1 = (x*onorm) @ W1
  k_gemm<FIN, FHID, 0><<<gemm_grid, 256, 0, stream>>>(x, W1p, onorm, nullptr, B1);
  // g1 = relu(agg(t1)*inorm + b1) * onorm
  k_agg<FHID, 0><<<(NN * (FHID / 2) + 255) / 256, 256, 0, stream>>>(B1, rp, csr, inorm, onorm, b1, B2);
  // agg2 = agg(g1)*inorm
  k_agg<FHID, 1><<<(NN * (FHID / 2) + 255) / 256, 256, 0, stream>>>(B2, rp, csr, inorm, nullptr, nullptr, B1);
  // g2 = relu(agg2 @ W2 + b2) * onorm
  k_gemm<FHID, FHID, 2><<<gemm_grid, 256, 0, stream>>>(B1, W2p, onorm, b2, B2);
  // t3 = g2 @ W3
  k_gemm<FHID, FCLS, 1><<<gemm_grid, 256, 0, stream>>>(B2, W3p, nullptr, nullptr, B1);
  // out = agg(t3)*inorm + b3
  k_agg<FCLS, 2><<<(NN * (FCLS / 2) + 255) / 256, 256, 0, stream>>>(B1, rp, csr, inorm, nullptr, b3, d_out);
}

// Round 4
// 421.767 us; speedup vs baseline: 1.8984x; 1.0694x over previous
//
#include <hip/hip_runtime.h>

#define NN 100000
#define NE 1600000
#define FIN 256
#define FHID 128
#define FCLS 64

// multisplit params: 512 dst-nodes per partition
#define SH1 9
#define P1 196
#define EPB 8192
#define NBLK_E ((NE + EPB - 1) / EPB)

typedef _Float16 f16;
typedef __attribute__((ext_vector_type(8))) _Float16 f16x8;
typedef __attribute__((ext_vector_type(2))) _Float16 f16x2;
typedef __attribute__((ext_vector_type(4))) float f32x4;
typedef __attribute__((ext_vector_type(2))) float f32x2;

// ---------------- pass A: per-block dst-partition histogram + outdeg ----------------
__global__ __launch_bounds__(256) void k_histA(const int* __restrict__ src, const int* __restrict__ dst,
                                               int* __restrict__ outdeg, int* __restrict__ hist2d) {
  __shared__ int lh[P1];
  int t = threadIdx.x;
  for (int i = t; i < P1; i += 256) lh[i] = 0;
  __syncthreads();
  int base = blockIdx.x * EPB;
  int cnt = NE - base; if (cnt > EPB) cnt = EPB;
  for (int i = t; i < cnt; i += 256) {
    atomicAdd(&outdeg[src[base + i]], 1);
    atomicAdd(&lh[dst[base + i] >> SH1], 1);
  }
  __syncthreads();
  for (int i = t; i < P1; i += 256) hist2d[blockIdx.x * P1 + i] = lh[i];
}

// ---------------- pass B: totals, partition bases, per-(block,partition) bases ----------------
__global__ __launch_bounds__(256) void k_pscan(const int* __restrict__ hist2d, int* __restrict__ totals,
                                               int* __restrict__ pbase, int* __restrict__ base2d,
                                               int* __restrict__ rp) {
  __shared__ int sm[256];
  int t = threadIdx.x;
  int tot = 0;
  if (t < P1) {
    for (int b = 0; b < NBLK_E; ++b) tot += hist2d[b * P1 + t];
    totals[t] = tot;
  }
  int v = (t < P1) ? tot : 0;
  int x = v;
  sm[t] = x;
  __syncthreads();
  for (int off = 1; off < 256; off <<= 1) {
    int y = (t >= off) ? sm[t - off] : 0;
    __syncthreads();
    x += y;
    sm[t] = x;
    __syncthreads();
  }
  if (t < P1) {
    int run = x - v;
    pbase[t] = run;
    for (int b = 0; b < NBLK_E; ++b) {
      base2d[b * P1 + t] = run;
      run += hist2d[b * P1 + t];
    }
  }
  if (t == 0) rp[NN] = NE;
}

// ---------------- pass C: per-block LDS counting sort -> contiguous partition runs ----------------
__global__ __launch_bounds__(256) void k_place(const int* __restrict__ src, const int* __restrict__ dst,
                                               const int* __restrict__ hist2d, const int* __restrict__ base2d,
                                               unsigned* __restrict__ staged) {
  __shared__ unsigned buf[EPB];
  __shared__ unsigned char prt[EPB];
  __shared__ int lofs[P1], lcur[P1], lbase[P1];
  __shared__ int sm[256];
  int t = threadIdx.x;
  int b = blockIdx.x;
  int v = 0;
  if (t < P1) {
    v = hist2d[b * P1 + t];
    lbase[t] = base2d[b * P1 + t];
    lcur[t] = 0;
  }
  int x = v;
  sm[t] = x;
  __syncthreads();
  for (int off = 1; off < 256; off <<= 1) {
    int y = (t >= off) ? sm[t - off] : 0;
    __syncthreads();
    x += y;
    sm[t] = x;
    __syncthreads();
  }
  if (t < P1) lofs[t] = x - v;
  __syncthreads();
  int base = b * EPB;
  int cnt = NE - base; if (cnt > EPB) cnt = EPB;
  for (int i = t; i < cnt; i += 256) {
    int s = src[base + i], d = dst[base + i];
    int p = d >> SH1;
    int pos = lofs[p] + atomicAdd(&lcur[p], 1);
    buf[pos] = ((unsigned)s << SH1) | (unsigned)(d & 511);
    prt[pos] = (unsigned char)p;
  }
  __syncthreads();
  for (int i = t; i < cnt; i += 256) {
    int p = prt[i];
    staged[lbase[p] + (i - lofs[p])] = buf[i];
  }
}

// ---------------- pass D: per-partition CSR build ----------------
__global__ __launch_bounds__(512) void k_buildp(const unsigned* __restrict__ staged, const int* __restrict__ totals,
                                                const int* __restrict__ pbase, int* __restrict__ rp,
                                                float* __restrict__ inorm, int* __restrict__ csr) {
  __shared__ int lcnt[512], lofs[512], lcur[512];
  int p = blockIdx.x, t = threadIdx.x;
  int pb = pbase[p], cnt = totals[p];
  lcnt[t] = 0;
  __syncthreads();
  const unsigned* sp = staged + pb;
  for (int i = t; i < cnt; i += 512) atomicAdd(&lcnt[sp[i] & 511], 1);
  __syncthreads();
  int v = lcnt[t];
  int x = v;
  lofs[t] = x;
  __syncthreads();
  for (int off = 1; off < 512; off <<= 1) {
    int y = (t >= off) ? lofs[t - off] : 0;
    __syncthreads();
    x += y;
    lofs[t] = x;
    __syncthreads();
  }
  int excl = x - v;
  lofs[t] = excl;
  lcur[t] = 0;
  int node = (p << SH1) + t;
  if (node < NN) {
    rp[node] = pb + excl;
    int dg = v < 1 ? 1 : v;
    inorm[node] = rsqrtf((float)dg);
  }
  __syncthreads();
  for (int i = t; i < cnt; i += 512) {
    unsigned e = sp[i];
    int d = e & 511;
    int pos = pb + lofs[d] + atomicAdd(&lcur[d], 1);
    csr[pos] = (int)(e >> SH1);
  }
}

__global__ __launch_bounds__(256) void k_onorm(const int* __restrict__ outdeg, float* __restrict__ onorm) {
  int i = blockIdx.x * 256 + threadIdx.x;
  if (i < NN) {
    int od = outdeg[i];
    if (od < 1) od = 1;
    onorm[i] = rsqrtf((float)od);
  }
}

// ---------------- weight pack: fragment-major f16 for mfma 16x16x32 ----------------
template <int K, int NW>
__global__ __launch_bounds__(256) void k_packw(const float* __restrict__ W, f16* __restrict__ Wp) {
  int idx = blockIdx.x * 256 + threadIdx.x;
  if (idx >= K * NW) return;
  constexpr int nT = NW / 16;
  int i = idx & 7;
  int l = (idx >> 3) & 63;
  int rest = idx >> 9;
  int t = rest % nT;
  int s = rest / nT;
  int k = s * 32 + (l >> 4) * 8 + i;
  int n = t * 16 + (l & 15);
  Wp[idx] = (f16)W[k * NW + n];
}

// ---------------- GEMM: [M=NN x K] @ [K x NW] via mfma_f32_16x16x32_f16 ----------------
// Output ALWAYS feature-sliced: Out[((col>>5)*NN + row)*32 + (col&31)], f16.
// MODE 0: A = f32 x (row-major), rows scaled by onorm.   (layer 1)
// MODE 1: A = f16 sliced [s][NN][32].                    (layer 3)
// MODE 2: A = f16 sliced; epilogue relu(+bias)*onorm.    (layer 2)
template <int K, int NW, int MODE>
__global__ __launch_bounds__(256) void k_gemm(const void* __restrict__ Asrc, const f16* __restrict__ Wp,
                                              const float* __restrict__ onorm, const float* __restrict__ bias,
                                              f16* __restrict__ Out) {
  constexpr int nS = K / 32, nT = NW / 16;
  int lane = threadIdx.x & 63;
  int w = threadIdx.x >> 6;
  int bm = blockIdx.x * 64 + w * 16;
  int arow = bm + (lane & 15);
  int koff = (lane >> 4) * 8;
  bool rowok = arow < NN;

  f32x4 acc[nT];
#pragma unroll
  for (int t = 0; t < nT; ++t) acc[t] = (f32x4){0.f, 0.f, 0.f, 0.f};

  float ascale = 0.0f;
  if (MODE == 0) ascale = rowok ? onorm[arow] : 0.0f;

  for (int s = 0; s < nS; ++s) {
    f16x8 a = {};
    if (rowok) {
      if (MODE == 0) {
        const float* ap = (const float*)Asrc + (size_t)arow * K + s * 32 + koff;
        f32x4 v0 = *(const f32x4*)ap;
        f32x4 v1 = *(const f32x4*)(ap + 4);
#pragma unroll
        for (int j = 0; j < 4; ++j) {
          a[j] = (f16)(v0[j] * ascale);
          a[4 + j] = (f16)(v1[j] * ascale);
        }
      } else {
        // sliced A: k-subtile s IS slice s (32 features per slice)
        a = *(const f16x8*)((const f16*)Asrc + ((size_t)s * NN + arow) * 32 + koff);
      }
    }
    const f16* bp = Wp + ((size_t)(s * nT) * 64 + lane) * 8;
#pragma unroll
    for (int t = 0; t < nT; ++t) {
      f16x8 bfr = *(const f16x8*)(bp + t * 512);
      acc[t] = __builtin_amdgcn_mfma_f32_16x16x32_f16(a, bfr, acc[t], 0, 0, 0);
    }
  }

  int crow0 = bm + (lane >> 4) * 4;
  int ccol = lane & 15;
#pragma unroll
  for (int t = 0; t < nT; ++t) {
#pragma unroll
    for (int r = 0; r < 4; ++r) {
      int row = crow0 + r;
      if (row >= NN) continue;
      int col = t * 16 + ccol;
      float v = acc[t][r];
      if (MODE == 2) v = fmaxf(v + bias[col], 0.f) * onorm[row];
      Out[((size_t)(col >> 5) * NN + row) * 32 + (col & 31)] = (f16)v;
    }
  }
}

// ---------------- sliced aggregation: gather-sum over CSR in-edges ----------------
// Feature tables are [NS][NN][32] f16 (64 B per node-slice-row = one cache line).
// blockIdx%8 pins a slice to 8/NS XCDs (round-robin XCD dispatch heuristic).
// MODE 0: out f16 sliced = relu(acc*inorm + bias) * onorm
// MODE 1: out f16 sliced = acc*inorm
// MODE 2: out f32 DENSE [NN][2*NS*32] = acc*inorm + bias   (final, NS=2 -> 64 cols)
template <int NS, int MODE>
__global__ __launch_bounds__(256) void k_aggs(const f16* __restrict__ src_arr, const int* __restrict__ rp,
                                              const int* __restrict__ csr, const float* __restrict__ inorm,
                                              const float* __restrict__ onorm, const float* __restrict__ bias,
                                              void* __restrict__ outp) {
  constexpr int XPS = 8 / NS;      // XCDs per slice
  constexpr int BPS = NN / 16;     // blocks per slice (16 nodes/block), 6250
  int bid = blockIdx.x;
  int r = bid & 7;
  int slice = r / XPS;
  int w = (bid >> 3) * XPS + (r % XPS);
  if (w >= BPS) return;
  int t = threadIdx.x;
  int node = w * 16 + (t >> 4);
  int lf = (t & 15) * 2;           // local feature (0..30, even)
  int beg = rp[node], end = rp[node + 1];
  const f16* sb = src_arr + (size_t)slice * NN * 32 + lf;
  float a0 = 0.f, a1 = 0.f;
  int e = beg;
  for (; e + 3 < end; e += 4) {
    int s0 = csr[e], s1 = csr[e + 1], s2 = csr[e + 2], s3 = csr[e + 3];
    f16x2 v0 = *(const f16x2*)(sb + (size_t)s0 * 32);
    f16x2 v1 = *(const f16x2*)(sb + (size_t)s1 * 32);
    f16x2 v2 = *(const f16x2*)(sb + (size_t)s2 * 32);
    f16x2 v3 = *(const f16x2*)(sb + (size_t)s3 * 32);
    a0 += ((float)v0[0] + (float)v1[0]) + ((float)v2[0] + (float)v3[0]);
    a1 += ((float)v0[1] + (float)v1[1]) + ((float)v2[1] + (float)v3[1]);
  }
  for (; e < end; ++e) {
    f16x2 v0 = *(const f16x2*)(sb + (size_t)csr[e] * 32);
    a0 += (float)v0[0];
    a1 += (float)v0[1];
  }
  float inn = inorm[node];
  int gf = slice * 32 + lf;        // global feature col
  if (MODE == 0) {
    float on = onorm[node];
    f16x2 o;
    o[0] = (f16)(fmaxf(a0 * inn + bias[gf], 0.f) * on);
    o[1] = (f16)(fmaxf(a1 * inn + bias[gf + 1], 0.f) * on);
    *(f16x2*)((f16*)outp + ((size_t)slice * NN + node) * 32 + lf) = o;
  } else if (MODE == 1) {
    f16x2 o;
    o[0] = (f16)(a0 * inn);
    o[1] = (f16)(a1 * inn);
    *(f16x2*)((f16*)outp + ((size_t)slice * NN + node) * 32 + lf) = o;
  } else {
    f32x2 o;
    o[0] = a0 * inn + bias[gf];
    o[1] = a1 * inn + bias[gf + 1];
    *(f32x2*)((float*)outp + (size_t)node * (NS * 32) + gf) = o;
  }
}

extern "C" void kernel_launch(void* const* d_in, const int* in_sizes, int n_in,
                              void* d_out, int out_size, void* d_ws, size_t ws_size,
                              hipStream_t stream) {
  const float* x = (const float*)d_in[0];
  const int* src = (const int*)d_in[1];
  const int* dst = (const int*)d_in[2];
  const float* W1 = (const float*)d_in[3];
  const float* b1 = (const float*)d_in[4];
  const float* W2 = (const float*)d_in[5];
  const float* b2 = (const float*)d_in[6];
  const float* W3 = (const float*)d_in[7];
  const float* b3 = (const float*)d_in[8];

  char* base = (char*)d_ws;
  size_t off = 0;
  auto take = [&](size_t bytes) -> void* {
    void* r = base + off;
    off += (bytes + 255) & ~(size_t)255;
    return r;
  };
  int* outdeg = (int*)take((size_t)NN * 4);
  float* onorm = (float*)take((size_t)NN * 4);
  float* inorm = (float*)take((size_t)NN * 4);
  int* rp = (int*)take((size_t)(NN + 1) * 4);
  int* totals = (int*)take((size_t)P1 * 4);
  int* pbase = (int*)take((size_t)P1 * 4);
  int* hist2d = (int*)take((size_t)NBLK_E * P1 * 4);
  int* base2d = (int*)take((size_t)NBLK_E * P1 * 4);
  unsigned* staged = (unsigned*)take((size_t)NE * 4);
  int* csr = (int*)take((size_t)NE * 4);
  f16* W1p = (f16*)take((size_t)FIN * FHID * 2);
  f16* W2p = (f16*)take((size_t)FHID * FHID * 2);
  f16* W3p = (f16*)take((size_t)FHID * FCLS * 2);
  f16* B1 = (f16*)take((size_t)NN * FHID * 2);
  f16* B2 = (f16*)take((size_t)NN * FHID * 2);

  hipMemsetAsync(outdeg, 0, (size_t)NN * 4, stream);

  k_histA<<<NBLK_E, 256, 0, stream>>>(src, dst, outdeg, hist2d);
  k_pscan<<<1, 256, 0, stream>>>(hist2d, totals, pbase, base2d, rp);
  k_place<<<NBLK_E, 256, 0, stream>>>(src, dst, hist2d, base2d, staged);
  k_buildp<<<P1, 512, 0, stream>>>(staged, totals, pbase, rp, inorm, csr);
  k_onorm<<<(NN + 255) / 256, 256, 0, stream>>>(outdeg, onorm);

  k_packw<FIN, FHID><<<(FIN * FHID + 255) / 256, 256, 0, stream>>>(W1, W1p);
  k_packw<FHID, FHID><<<(FHID * FHID + 255) / 256, 256, 0, stream>>>(W2, W2p);
  k_packw<FHID, FCLS><<<(FHID * FCLS + 255) / 256, 256, 0, stream>>>(W3, W3p);

  const int gemm_grid = (NN + 63) / 64;
  const int agg4_grid = ((4 * (NN / 16) + 7) / 8) * 8;   // 25000
  const int agg2_grid = ((2 * (NN / 16) + 7) / 8) * 8;   // 12504
  // layer 1: t1 = (x*onorm) @ W1  -> sliced B1
  k_gemm<FIN, FHID, 0><<<gemm_grid, 256, 0, stream>>>(x, W1p, onorm, nullptr, B1);
  // g1 = relu(agg(t1)*inorm + b1) * onorm  -> sliced B2
  k_aggs<4, 0><<<agg4_grid, 256, 0, stream>>>(B1, rp, csr, inorm, onorm, b1, B2);
  // agg2 = agg(g1)*inorm  -> sliced B1
  k_aggs<4, 1><<<agg4_grid, 256, 0, stream>>>(B2, rp, csr, inorm, nullptr, nullptr, B1);
  // g2 = relu(agg2 @ W2 + b2) * onorm  -> sliced B2
  k_gemm<FHID, FHID, 2><<<gemm_grid, 256, 0, stream>>>(B1, W2p, onorm, b2, B2);
  // t3 = g2 @ W3  -> sliced B1 (2 slices used)
  k_gemm<FHID, FCLS, 1><<<gemm_grid, 256, 0, stream>>>(B2, W3p, nullptr, nullptr, B1);
  // out = agg(t3)*inorm + b3  -> dense f32 d_out
  k_aggs<2, 2><<<agg2_grid, 256, 0, stream>>>(B1, rp, csr, inorm, nullptr, b3, d_out);
}